// Round 1
// baseline (267.719 us; speedup 1.0000x reference)
//
#include <hip/hip_runtime.h>
#include <hip/hip_bf16.h>
#include <stdint.h>

#define DIM 128

typedef __attribute__((ext_vector_type(8))) short short8;
typedef __attribute__((ext_vector_type(4))) float f32x4;
typedef __attribute__((ext_vector_type(8))) unsigned short ushort8;

__device__ __forceinline__ float bf2f(unsigned short u) {
    unsigned int x = ((unsigned int)u) << 16;
    return __builtin_bit_cast(float, x);
}
__device__ __forceinline__ unsigned short f2bf(float f) {
    unsigned int x = __builtin_bit_cast(unsigned int, f);
    x += 0x7fffu + ((x >> 16) & 1u);
    return (unsigned short)(x >> 16);
}

// ---------------------------------------------------------------------------
// Kernel 0: transpose W1 slices to bf16 [N][K] layouts for MFMA B-fragments.
//   W1aT [128][128]: W1aT[n][k] = W1[k][n]            (rows 0..127   = |ni-nj| block)
//   W1bcT[256][128]: c<128: W1[128+k][c]              (res_i block -> P cols 0..127)
//                    c>=128: W1[256+k][c-128]         (res_j block -> P cols 128..255)
// ---------------------------------------------------------------------------
__global__ void prep_weights(const float* __restrict__ W1,
                             unsigned short* __restrict__ W1aT,
                             unsigned short* __restrict__ W1bcT) {
    int t = blockIdx.x * 256 + threadIdx.x;
    if (t < 128 * 128) {
        int n = t >> 7, k = t & 127;
        W1aT[t] = f2bf(W1[k * DIM + n]);
    } else {
        int t2 = t - 128 * 128;  // 0 .. 256*128-1
        int c = t2 >> 7, k = t2 & 127;
        int row = 128 + ((c >> 7) << 7) + k;
        W1bcT[t2] = f2bf(W1[row * DIM + (c & 127)]);
    }
}

// ---------------------------------------------------------------------------
// Kernel 1: P[n][0:256] = (nf[n]-centroid[g]) @ [W1b | W1c]  (+ b1 on cols<128)
// 64 nodes/block, 512 threads = 8 waves: wave tile 32 nodes x 64 cols.
// A (res, bf16) staged in LDS with byte ^= (row&7)<<4 swizzle; B in registers.
// ---------------------------------------------------------------------------
__global__ __launch_bounds__(512) void precompute_P(
    const float* __restrict__ nf, const float* __restrict__ centroid,
    const unsigned short* __restrict__ W1bcT, const float* __restrict__ b1,
    unsigned short* __restrict__ P, int npg)
{
    __shared__ char sA[64 * 256];  // bf16 [64 rows][128 k], swizzled
    const int t = threadIdx.x;
    const int n0 = blockIdx.x * 64;

    {   // stage residual -> bf16 LDS
        int row = t >> 3;            // 64 rows, 8 threads each
        int c0 = (t & 7) * 16;
        int n = n0 + row;
        int g = n / npg;
        const f32x4* nv = (const f32x4*)(nf + (size_t)n * DIM + c0);
        const f32x4* cv = (const f32x4*)(centroid + (size_t)g * DIM + c0);
        unsigned short sh[16];
#pragma unroll
        for (int u = 0; u < 4; ++u) {
            f32x4 a = nv[u], c = cv[u];
#pragma unroll
            for (int x = 0; x < 4; ++x) sh[u * 4 + x] = f2bf(a[x] - c[x]);
        }
#pragma unroll
        for (int v = 0; v < 2; ++v) {
            int inrow = c0 * 2 + v * 16;
            int phys = row * 256 + (inrow ^ ((row & 7) << 4));
            *(short8*)(sA + phys) = *(const short8*)(sh + v * 8);
        }
    }

    const int wid = t >> 6, l = t & 63, lo = l & 15, hi = l >> 4;
    const int wm = wid & 1, wn = wid >> 1;  // wm: node-half(32), wn: col-quarter(64) of 256

    short8 B[4][4];  // [n-tile][k-step]
#pragma unroll
    for (int nt = 0; nt < 4; ++nt) {
        int row = wn * 64 + nt * 16 + lo;
        const short8* wp = (const short8*)(W1bcT + (size_t)row * DIM + hi * 8);
#pragma unroll
        for (int kk = 0; kk < 4; ++kk) B[nt][kk] = wp[kk * 4];  // +kk*32 shorts
    }

    __syncthreads();

    f32x4 acc[2][4];
#pragma unroll
    for (int mt = 0; mt < 2; ++mt)
#pragma unroll
        for (int nt = 0; nt < 4; ++nt) acc[mt][nt] = (f32x4)0.0f;

#pragma unroll
    for (int kk = 0; kk < 4; ++kk) {
        short8 a[2];
#pragma unroll
        for (int mt = 0; mt < 2; ++mt) {
            int row = wm * 32 + mt * 16 + lo;
            int inrow = kk * 64 + hi * 16;
            int phys = row * 256 + (inrow ^ ((row & 7) << 4));
            a[mt] = *(const short8*)(sA + phys);
        }
#pragma unroll
        for (int mt = 0; mt < 2; ++mt)
#pragma unroll
            for (int nt = 0; nt < 4; ++nt)
                acc[mt][nt] = __builtin_amdgcn_mfma_f32_16x16x32_bf16(
                    a[mt], B[nt][kk], acc[mt][nt], 0, 0, 0);
    }

    // epilogue: +b1 on cols<128 (fold bias into P's i-half), store bf16
#pragma unroll
    for (int nt = 0; nt < 4; ++nt) {
        int col = wn * 64 + nt * 16 + lo;
        float bb = (col < DIM) ? b1[col] : 0.0f;
#pragma unroll
        for (int mt = 0; mt < 2; ++mt)
#pragma unroll
            for (int q = 0; q < 4; ++q) {
                int n = n0 + wm * 32 + mt * 16 + hi * 4 + q;
                P[(size_t)n * 256 + col] = f2bf(acc[mt][nt][q] + bb);
            }
    }
}

// ---------------------------------------------------------------------------
// Kernel 2: per-edge  score = relu(|ni-nj| @ W1a + P[i][0:128] + P[j][128:256]) @ W2 + b2
// 64 edges/block, 256 threads = 4 waves: wave tile 32 edges x 64 cols.
// D (|ni-nj| bf16) in swizzled LDS; W1aT in registers; P-sum in padded fp32 LDS;
// fused relu*W2 + shuffle reduction (H never materialized).
// ---------------------------------------------------------------------------
__global__ __launch_bounds__(256) void edge_kernel(
    const float* __restrict__ nf, const int* __restrict__ idx,
    const unsigned short* __restrict__ P, const unsigned short* __restrict__ W1aT,
    const float* __restrict__ W2, const float* __restrict__ b2,
    float* __restrict__ out, int E)
{
    __shared__ char  sD[64 * 256];    // bf16 [64][128] swizzled
    __shared__ float sS[64 * 132];    // fp32, stride 132 (2-way banks = free)
    __shared__ float sR[2][64];
    const int t = threadIdx.x;
    const int e0 = blockIdx.x * 64;

    {   // staging: 4 threads per edge, 32 cols each
        int e = t >> 2;
        int ge = e0 + e;
        int jj = 0, ii = 0;
        if (ge < E) { jj = idx[ge]; ii = idx[E + ge]; }  // edge_index[0]=j, [1]=i
        int c0 = (t & 3) * 32;
        const f32x4* av = (const f32x4*)(nf + (size_t)ii * DIM + c0);
        const f32x4* bv = (const f32x4*)(nf + (size_t)jj * DIM + c0);
        unsigned short sh[32];
#pragma unroll
        for (int u = 0; u < 8; ++u) {
            f32x4 a = av[u], b = bv[u];
#pragma unroll
            for (int x = 0; x < 4; ++x) sh[u * 4 + x] = f2bf(fabsf(a[x] - b[x]));
        }
#pragma unroll
        for (int v = 0; v < 4; ++v) {
            int inrow = c0 * 2 + v * 16;
            int phys = e * 256 + (inrow ^ ((e & 7) << 4));
            *(short8*)(sD + phys) = *(const short8*)(sh + v * 8);
        }
        // S[e][k] = P[i][k] + P[j][128+k]   (b1 already folded into P i-half)
        const ushort8* pi = (const ushort8*)(P + (size_t)ii * 256 + c0);
        const ushort8* pj = (const ushort8*)(P + (size_t)jj * 256 + DIM + c0);
#pragma unroll
        for (int u = 0; u < 4; ++u) {
            ushort8 pa = pi[u], pb = pj[u];
            float s[8];
#pragma unroll
            for (int x = 0; x < 8; ++x) s[x] = bf2f(pa[x]) + bf2f(pb[x]);
            *(f32x4*)(sS + e * 132 + c0 + u * 8)     = *(const f32x4*)(s);
            *(f32x4*)(sS + e * 132 + c0 + u * 8 + 4) = *(const f32x4*)(s + 4);
        }
    }

    const int wid = t >> 6, l = t & 63, lo = l & 15, hi = l >> 4;
    const int wm = wid & 1, wn = wid >> 1;  // wm: edge-half(32), wn: col-half(64)

    short8 B[4][4];
#pragma unroll
    for (int nt = 0; nt < 4; ++nt) {
        int row = wn * 64 + nt * 16 + lo;
        const short8* wp = (const short8*)(W1aT + (size_t)row * DIM + hi * 8);
#pragma unroll
        for (int kk = 0; kk < 4; ++kk) B[nt][kk] = wp[kk * 4];
    }
    float w2v[4];
#pragma unroll
    for (int nt = 0; nt < 4; ++nt) w2v[nt] = W2[wn * 64 + nt * 16 + lo];

    __syncthreads();

    f32x4 acc[2][4];
#pragma unroll
    for (int mt = 0; mt < 2; ++mt)
#pragma unroll
        for (int nt = 0; nt < 4; ++nt) acc[mt][nt] = (f32x4)0.0f;

#pragma unroll
    for (int kk = 0; kk < 4; ++kk) {
        short8 a[2];
#pragma unroll
        for (int mt = 0; mt < 2; ++mt) {
            int row = wm * 32 + mt * 16 + lo;
            int inrow = kk * 64 + hi * 16;
            int phys = row * 256 + (inrow ^ ((row & 7) << 4));
            a[mt] = *(const short8*)(sD + phys);
        }
#pragma unroll
        for (int mt = 0; mt < 2; ++mt)
#pragma unroll
            for (int nt = 0; nt < 4; ++nt)
                acc[mt][nt] = __builtin_amdgcn_mfma_f32_16x16x32_bf16(
                    a[mt], B[nt][kk], acc[mt][nt], 0, 0, 0);
    }

    // fused epilogue: h = relu(acc + S); partial = sum_cols h * W2[col]
    float p[2][4];
#pragma unroll
    for (int mt = 0; mt < 2; ++mt)
#pragma unroll
        for (int q = 0; q < 4; ++q) {
            int el = wm * 32 + mt * 16 + hi * 4 + q;
            float s = 0.0f;
#pragma unroll
            for (int nt = 0; nt < 4; ++nt) {
                int col = wn * 64 + nt * 16 + lo;
                float h = acc[mt][nt][q] + sS[el * 132 + col];
                h = fmaxf(h, 0.0f);
                s += h * w2v[nt];
            }
            p[mt][q] = s;
        }
    // reduce over the 16 col-lanes (lo bits)
#pragma unroll
    for (int d = 1; d < 16; d <<= 1)
#pragma unroll
        for (int mt = 0; mt < 2; ++mt)
#pragma unroll
            for (int q = 0; q < 4; ++q)
                p[mt][q] += __shfl_xor(p[mt][q], d);

    if (lo == 0) {
#pragma unroll
        for (int mt = 0; mt < 2; ++mt)
#pragma unroll
            for (int q = 0; q < 4; ++q)
                sR[wn][wm * 32 + mt * 16 + hi * 4 + q] = p[mt][q];
    }
    __syncthreads();
    if (t < 64) {
        float v = sR[0][t] + sR[1][t] + b2[0];
        int ge = e0 + t;
        if (ge < E) out[ge] = v;
    }
}

// ---------------------------------------------------------------------------
extern "C" void kernel_launch(void* const* d_in, const int* in_sizes, int n_in,
                              void* d_out, int out_size, void* d_ws, size_t ws_size,
                              hipStream_t stream) {
    const float* nf       = (const float*)d_in[0];
    const int*   idx      = (const int*)d_in[1];
    const float* centroid = (const float*)d_in[2];
    // d_in[3] = bs (device scalar, derived from in_sizes instead)
    const float* W1       = (const float*)d_in[4];
    const float* b1       = (const float*)d_in[5];
    const float* W2       = (const float*)d_in[6];
    const float* b2       = (const float*)d_in[7];
    float* out = (float*)d_out;

    const int n_nodes = in_sizes[0] / DIM;
    const int E       = in_sizes[1] / 2;
    const int bs      = in_sizes[2] / DIM;
    const int npg     = n_nodes / bs;

    unsigned short* P     = (unsigned short*)d_ws;                   // [n_nodes][256] bf16
    unsigned short* W1aT  = P + (size_t)n_nodes * 256;               // [128][128] bf16
    unsigned short* W1bcT = W1aT + 128 * 128;                        // [256][128] bf16

    prep_weights<<<(128 * 384) / 256, 256, 0, stream>>>(W1, W1aT, W1bcT);
    precompute_P<<<n_nodes / 64, 512, 0, stream>>>(nf, centroid, W1bcT, b1, P, npg);
    edge_kernel<<<(E + 63) / 64, 256, 0, stream>>>(nf, idx, P, W1aT, W2, b2, out, E);
}

// Round 2
// 188.507 us; speedup vs baseline: 1.4202x; 1.4202x over previous
//
#include <hip/hip_runtime.h>
#include <hip/hip_bf16.h>
#include <stdint.h>

#define DIM 128

typedef __attribute__((ext_vector_type(8))) short short8;
typedef __attribute__((ext_vector_type(4))) float f32x4;
typedef __attribute__((ext_vector_type(8))) unsigned short ushort8;

__device__ __forceinline__ float bf2f(unsigned short u) {
    unsigned int x = ((unsigned int)u) << 16;
    return __builtin_bit_cast(float, x);
}
__device__ __forceinline__ unsigned short f2bf(float f) {
    unsigned int x = __builtin_bit_cast(unsigned int, f);
    x += 0x7fffu + ((x >> 16) & 1u);
    return (unsigned short)(x >> 16);
}

// ---------------------------------------------------------------------------
// Kernel 0: nf fp32 -> bf16 (halves edge-gather bytes)
// ---------------------------------------------------------------------------
__global__ void nf_to_bf16(const float* __restrict__ nf,
                           unsigned short* __restrict__ nf16, int total8) {
    int o = blockIdx.x * 256 + threadIdx.x;
    if (o >= total8) return;
    const f32x4* p = (const f32x4*)(nf + (size_t)o * 8);
    f32x4 x0 = p[0], x1 = p[1];
    ushort8 r;
#pragma unroll
    for (int x = 0; x < 4; ++x) { r[x] = f2bf(x0[x]); r[x + 4] = f2bf(x1[x]); }
    *(ushort8*)(nf16 + (size_t)o * 8) = r;
}

// ---------------------------------------------------------------------------
// Kernel 1: pack W1^T (full 3*DIM K) into exact MFMA B-fragment load order:
//   pack[(((T*12 + s)*64 + l)*8 + x] = W1[k][col],
//   col = T*16 + (l&15), k = s*32 + (l>>4)*8 + x.
// A wave's B-frag load is then a fully coalesced 16B/lane read.
// ---------------------------------------------------------------------------
__global__ void pack_W1(const float* __restrict__ W1,
                        unsigned short* __restrict__ pack) {
    int o = blockIdx.x * 256 + threadIdx.x;   // 0 .. 8*12*64*8-1 = 49151
    int x = o & 7, l = (o >> 3) & 63, o2 = o >> 9;  // o2: 0..95
    int s = o2 % 12, T = o2 / 12;
    int col = T * 16 + (l & 15);
    int k = s * 32 + (l >> 4) * 8 + x;
    pack[o] = f2bf(W1[k * DIM + col]);
}

// ---------------------------------------------------------------------------
// Kernel 2: per-edge fused K=384 GEMM.
//   A[e][0:128]=|ni-nj|, [128:256]=res_i, [256:384]=res_j   (bf16, swizzled LDS)
//   score = relu(A @ W1 + b1) @ W2 + b2, H never materialized.
// 32 edges/block, 256 thr = 4 waves, wave tile 32 edges x 32 cols.
// LDS 24.6KB -> 6 blocks/CU target (launch_bounds 256,6).
// ---------------------------------------------------------------------------
__global__ __launch_bounds__(256, 6) void edge_kernel(
    const unsigned short* __restrict__ nf16, const int* __restrict__ idx,
    const unsigned short* __restrict__ pack, const float* __restrict__ centroid,
    const float* __restrict__ b1, const float* __restrict__ W2,
    const float* __restrict__ b2, float* __restrict__ out, int E, int npg)
{
    __shared__ char  sA[32 * 768];   // bf16 [32 edges][384 k], byte^((row&7)<<4) swizzle
    __shared__ float sR[4][32];
    const int t = threadIdx.x;
    const int e0 = blockIdx.x * 32;

    {   // staging: 8 threads/edge, 16 k-cols each; d, res_i, res_j
        int e = t >> 3;
        int c0 = (t & 7) * 16;
        int ge = e0 + e;
        int jj = 0, ii = 0;
        if (ge < E) { jj = idx[ge]; ii = idx[E + ge]; }  // [0]=j, [1]=i
        int gi = ii / npg, gj = jj / npg;
        const ushort8* pi = (const ushort8*)(nf16 + (size_t)ii * DIM + c0);
        const ushort8* pj = (const ushort8*)(nf16 + (size_t)jj * DIM + c0);
        const f32x4* civ = (const f32x4*)(centroid + (size_t)gi * DIM + c0);
        const f32x4* cjv = (const f32x4*)(centroid + (size_t)gj * DIM + c0);
        int rs = e * 768, sw = (e & 7) << 4;
#pragma unroll
        for (int v = 0; v < 2; ++v) {
            ushort8 av = pi[v], bv = pj[v];
            f32x4 ci0 = civ[v * 2], ci1 = civ[v * 2 + 1];
            f32x4 cj0 = cjv[v * 2], cj1 = cjv[v * 2 + 1];
            unsigned short d[8], ri[8], rj[8];
#pragma unroll
            for (int x = 0; x < 8; ++x) {
                float a = bf2f(av[x]), b = bf2f(bv[x]);
                float ci_ = (x < 4) ? ci0[x] : ci1[x - 4];
                float cj_ = (x < 4) ? cj0[x] : cj1[x - 4];
                d[x]  = f2bf(fabsf(a - b));
                ri[x] = f2bf(a - ci_);
                rj[x] = f2bf(b - cj_);
            }
            int inb = c0 * 2 + v * 16;
            *(short8*)(sA + rs + ((inb      ) ^ sw)) = *(const short8*)d;
            *(short8*)(sA + rs + ((inb + 256) ^ sw)) = *(const short8*)ri;
            *(short8*)(sA + rs + ((inb + 512) ^ sw)) = *(const short8*)rj;
        }
    }
    __syncthreads();

    const int l = t & 63, wn = t >> 6, lo = l & 15, hi = l >> 4;
    const short8* bp = (const short8*)pack;

    f32x4 acc[2][2];
#pragma unroll
    for (int mt = 0; mt < 2; ++mt)
#pragma unroll
        for (int nt = 0; nt < 2; ++nt) acc[mt][nt] = (f32x4)0.0f;

#pragma unroll
    for (int kg = 0; kg < 3; ++kg) {
        short8 B[2][4];
#pragma unroll
        for (int nt = 0; nt < 2; ++nt)
#pragma unroll
            for (int kk = 0; kk < 4; ++kk)
                B[nt][kk] = bp[((wn * 2 + nt) * 12 + kg * 4 + kk) * 64 + l];
#pragma unroll
        for (int kk = 0; kk < 4; ++kk) {
            short8 a[2];
#pragma unroll
            for (int mt = 0; mt < 2; ++mt) {
                int row = mt * 16 + lo;
                int inrow = kg * 256 + kk * 64 + hi * 16;
                a[mt] = *(const short8*)(sA + row * 768 + (inrow ^ ((row & 7) << 4)));
            }
#pragma unroll
            for (int mt = 0; mt < 2; ++mt)
#pragma unroll
                for (int nt = 0; nt < 2; ++nt)
                    acc[mt][nt] = __builtin_amdgcn_mfma_f32_16x16x32_bf16(
                        a[mt], B[nt][kk], acc[mt][nt], 0, 0, 0);
        }
    }

    // fused epilogue: relu(acc + b1) . W2, shuffle-reduce over 16 col-lanes
    float b1v[2], w2v[2];
#pragma unroll
    for (int nt = 0; nt < 2; ++nt) {
        int col = wn * 32 + nt * 16 + lo;
        b1v[nt] = b1[col];
        w2v[nt] = W2[col];
    }
#pragma unroll
    for (int mt = 0; mt < 2; ++mt)
#pragma unroll
        for (int q = 0; q < 4; ++q) {
            float s = 0.0f;
#pragma unroll
            for (int nt = 0; nt < 2; ++nt)
                s += fmaxf(acc[mt][nt][q] + b1v[nt], 0.0f) * w2v[nt];
            s += __shfl_xor(s, 1);
            s += __shfl_xor(s, 2);
            s += __shfl_xor(s, 4);
            s += __shfl_xor(s, 8);
            if (lo == 0) sR[wn][mt * 16 + hi * 4 + q] = s;
        }
    __syncthreads();
    if (t < 32) {
        int ge = e0 + t;
        if (ge < E)
            out[ge] = sR[0][t] + sR[1][t] + sR[2][t] + sR[3][t] + b2[0];
    }
}

// ---------------------------------------------------------------------------
extern "C" void kernel_launch(void* const* d_in, const int* in_sizes, int n_in,
                              void* d_out, int out_size, void* d_ws, size_t ws_size,
                              hipStream_t stream) {
    const float* nf       = (const float*)d_in[0];
    const int*   idx      = (const int*)d_in[1];
    const float* centroid = (const float*)d_in[2];
    const float* W1       = (const float*)d_in[4];
    const float* b1       = (const float*)d_in[5];
    const float* W2       = (const float*)d_in[6];
    const float* b2       = (const float*)d_in[7];
    float* out = (float*)d_out;

    const int n_nodes = in_sizes[0] / DIM;
    const int E       = in_sizes[1] / 2;
    const int bs      = in_sizes[2] / DIM;
    const int npg     = n_nodes / bs;

    unsigned short* nf16 = (unsigned short*)d_ws;                 // [n_nodes][128] bf16
    unsigned short* pack = nf16 + (size_t)n_nodes * DIM;          // 49152 bf16

    int total8 = n_nodes * DIM / 8;
    nf_to_bf16<<<(total8 + 255) / 256, 256, 0, stream>>>(nf, nf16, total8);
    pack_W1<<<192, 256, 0, stream>>>(W1, pack);
    edge_kernel<<<(E + 31) / 32, 256, 0, stream>>>(nf16, idx, pack, centroid,
                                                   b1, W2, b2, out, E, npg);
}